// Round 4
// baseline (513.559 us; speedup 1.0000x reference)
//
#include <hip/hip_runtime.h>
#include <cstdint>
#include <cstddef>

typedef __bf16 bf16_t;
typedef __bf16 bf16x8 __attribute__((ext_vector_type(8)));
typedef float  f32x4  __attribute__((ext_vector_type(4)));

#define DHW   25088
#define SCALE 0.17677669529663687f  /* 32^-0.5 */

__device__ inline f32x4 mfma16(bf16x8 a, bf16x8 b, f32x4 c) {
  return __builtin_amdgcn_mfma_f32_16x16x32_bf16(a, b, c, 0, 0, 0);
}

// window-order row -> global (rolled) token row
__device__ inline size_t wrow_to_grow(int orow) {
  int win = orow / 98, tok = orow % 98;
  int b = win >> 8, wr = win & 255;
  int bd = wr >> 6, bh = (wr >> 3) & 7, bwi = wr & 7;
  int md = tok / 49, mh = (tok / 7) % 7, mw = tok % 7;
  int d = (bd * 2 + md + 1) & 7;
  int h = bh * 7 + mh + 3; if (h >= 56) h -= 56;
  int w = bwi * 7 + mw + 3; if (w >= 56) w -= 56;
  return (size_t)b * DHW + (size_t)((d * 56 + h) * 56 + w);
}

// ---------------- K0: weight cast + bias/mask table (merged) ----------
__global__ __launch_bounds__(256) void prep_all_kernel(
    const float* __restrict__ qkv_w, const float* __restrict__ proj_w,
    const float* __restrict__ fc1_w, const float* __restrict__ rel_bias,
    const float* __restrict__ mask,
    bf16_t* __restrict__ wq, bf16_t* __restrict__ wp, bf16_t* __restrict__ wf,
    bf16_t* __restrict__ bmr)
{
  int idx = blockIdx.x * 256 + threadIdx.x;
  if (idx < 110592) { wq[idx] = (bf16_t)qkv_w[idx]; return; }
  idx -= 110592;
  if (idx < 36864) { wp[idx] = (bf16_t)proj_w[idx]; return; }
  idx -= 36864;
  if (idx < 36864) { wf[idx] = (bf16_t)fc1_w[idx]; return; }
  idx -= 36864;
  if (idx >= 688128) return;
  int e    = idx & 31;
  int lane = (idx >> 5) & 63;
  int t2   = idx >> 11;
  int mt   = t2 % 7;
  int wh   = t2 / 7;
  int type = wh / 6, h = wh - type * 6;
  int winb = ((type & 4) ? 3 : 0) * 64 + ((type & 2) ? 7 : 0) * 8 + ((type & 1) ? 7 : 0);
  int g = lane >> 4, li = lane & 15;
  int nt2 = e >> 2, v = e & 3;
  int row = mt * 16 + g * 4 + v;
  int col = nt2 * 16 + li;
  float val = -1e30f;
  if (row < 98 && col < 98 && nt2 < 7) {
    int di = row / 49 - col / 49 + 1;
    int hi = (row / 7) % 7 - (col / 7) % 7 + 6;
    int wi = row % 7 - col % 7 + 6;
    int rid = di * 169 + hi * 13 + wi;
    val = mask[winb * 9604 + row * 98 + col] + rel_bias[rid * 6 + h];
  }
  bmr[idx] = (bf16_t)val;
}

// ---------------- K1: fused per-window block, 14 waves, 4 barriers ----
// wave = (wm, wn): wm = m-stripe (7), wn = N-half / head-triple.
// B-fragments for all three GEMMs are loaded DIRECTLY from L2 (no LDS
// staging, no per-tile barriers). Phases: LN -> QKV -> attn -> proj -> fc1.
__global__ __launch_bounds__(896) void fused_kernel(
    const float* __restrict__ x, const float* __restrict__ gw,
    const float* __restrict__ bw_, const bf16_t* __restrict__ wq,
    const float* __restrict__ qkv_b, const bf16_t* __restrict__ wp,
    const float* __restrict__ proj_b, const bf16_t* __restrict__ wf,
    const float* __restrict__ fc1_b, const bf16_t* __restrict__ bmr,
    float* __restrict__ out)
{
  __shared__ __align__(16) char smem[152384];
  bf16_t* U  = (bf16_t*)smem;                    // 17920: 14 PSc slots (gwb overlay)
  bf16_t* Qs = (bf16_t*)(smem + 17920);          // 39200: Q (scaled) -> attn out
  bf16_t* Ks = (bf16_t*)(smem + 57120);          // 39200: K -> C1 (proj out)
  bf16_t* Vt = (bf16_t*)(smem + 96320);          // 52224: V transposed [d][tok]
  float*  qb = (float*)(smem + 148544);          // 576 f32 qkv bias
  float*  pbuf = (float*)(smem + 150848);        // 192 f32 proj bias
  float*  fbuf = (float*)(smem + 151616);        // 192 f32 fc1 bias
  float* gwb = (float*)smem;                     // 384 f32 LN gamma/beta (PSc overlay)

  #define PSc(w, r, c) U[(w) * 640 + (r) * 40 + (c)]
  #define QS(r, c)     Qs[(r) * 200 + (c)]
  #define KS(r, c)     Ks[(r) * 200 + (c)]
  #define VT(d, t)     Vt[(d) * 136 + (t)]

  int win  = blockIdx.x;
  int winb = win & 255;
  int type = (((winb >> 6) == 3) ? 4 : 0) | ((((winb >> 3) & 7) == 7) ? 2 : 0)
           | (((winb & 7) == 7) ? 1 : 0);
  int tid  = threadIdx.x;
  int wid  = tid >> 6, lane = tid & 63;
  int wn = wid & 1, wm = wid >> 1;               // wm 0..6, wn 0..1
  int g = lane >> 4, li = lane & 15;

  // small tables + V token-pad zero (cols 96..127; 96,97 overwritten by real V)
  if (tid < 192) { gwb[tid] = gw[tid]; gwb[192 + tid] = bw_[tid]; }
  if (tid < 576) qb[tid] = qkv_b[tid];
  if (tid >= 576 && tid < 768) pbuf[tid - 576] = proj_b[tid - 576];
  if (tid >= 768 && tid < 896) fbuf[tid - 768] = fc1_b[tid - 768];
  if (tid < 64) fbuf[128 + tid] = fc1_b[128 + tid];
  if (tid < 768) {
    uint4 z = {0u, 0u, 0u, 0u};
    int d = tid >> 2, part = tid & 3;
    *(uint4*)&VT(d, 96 + part * 8) = z;
  }

  // ---- LN -> A fragments directly in registers (duplicated per wn) ----
  int r = wm * 16 + li;
  float v[48];
  if (r < 98) {
    size_t growr = wrow_to_grow(win * 98 + r);
    const float* xr = x + growr * 192 + g * 8;
    #pragma unroll
    for (int ks = 0; ks < 6; ks++) {
      *(float4*)&v[ks * 8]     = *(const float4*)(xr + ks * 32);
      *(float4*)&v[ks * 8 + 4] = *(const float4*)(xr + ks * 32 + 4);
    }
  } else {
    #pragma unroll
    for (int i = 0; i < 48; i++) v[i] = 0.f;
  }
  float s = 0.f, sq = 0.f;
  #pragma unroll
  for (int i = 0; i < 48; i++) { s += v[i]; sq += v[i] * v[i]; }
  s += __shfl_xor(s, 16, 64); sq += __shfl_xor(sq, 16, 64);
  s += __shfl_xor(s, 32, 64); sq += __shfl_xor(sq, 32, 64);
  float mu   = s * (1.0f / 192.0f);
  float var  = sq * (1.0f / 192.0f) - mu * mu;
  float rstd = rsqrtf(var + 1e-5f);
  __syncthreads();                       // BARRIER 1: tables staged
  bf16x8 afr[6];
  #pragma unroll
  for (int ks = 0; ks < 6; ks++) {
    bf16x8 t;
    #pragma unroll
    for (int j = 0; j < 8; j++) {
      int c = ks * 32 + g * 8 + j;
      t[j] = (r < 98) ? (bf16_t)((v[ks * 8 + j] - mu) * rstd * gwb[c] + gwb[192 + c])
                      : (bf16_t)0.0f;
    }
    afr[ks] = t;
  }

  // ---- QKV GEMM: [112x192] @ wq^T -> Qs (scaled) / Ks / Vt ----
  // B-fragments direct from L2; no barriers in this loop.
  for (int nt = 0; nt < 9; nt++) {
    const bf16_t* bp0 = wq + ((size_t)nt * 64 + (wn * 2 + 0) * 16 + li) * 192 + g * 8;
    const bf16_t* bp1 = bp0 + 16 * 192;
    f32x4 acc[2] = {};
    #pragma unroll
    for (int ks = 0; ks < 6; ks++) {
      bf16x8 b0 = *(const bf16x8*)(bp0 + ks * 32);
      bf16x8 b1 = *(const bf16x8*)(bp1 + ks * 32);
      acc[0] = mfma16(afr[ks], b0, acc[0]);
      acc[1] = mfma16(afr[ks], b1, acc[1]);
    }
    #pragma unroll
    for (int nl = 0; nl < 2; nl++)
    #pragma unroll
    for (int vv = 0; vv < 4; vv++) {
      int row = wm * 16 + g * 4 + vv;
      if (row < 98) {
        int col = nt * 64 + (wn * 2 + nl) * 16 + li;
        float val = acc[nl][vv] + qb[col];
        if (nt < 3)      QS(row, col)       = (bf16_t)(val * SCALE);
        else if (nt < 6) KS(row, col - 192) = (bf16_t)val;
        else             VT(col - 384, row) = (bf16_t)val;
      }
    }
  }
  __syncthreads();                       // BARRIER 2: Q/K/V staged

  // ---- attention: wave (wm, wn) -> m-stripe wm, heads wn*3..wn*3+2 ----
  int mt  = wm;
  int rq  = mt * 16 + li;
  int rqc = rq < 98 ? rq : 97;           // pad lanes read a real row; bm masks pads
  for (int hh = 0; hh < 3; hh++) {
    int h = wn * 3 + hh;
    const bf16_t* bmp = bmr + ((((size_t)(type * 6 + h)) * 7 + mt) * 64 + lane) * 32;
    bf16x8 bm0 = *(const bf16x8*)(bmp);
    bf16x8 bm1 = *(const bf16x8*)(bmp + 8);
    bf16x8 bm2 = *(const bf16x8*)(bmp + 16);
    bf16x8 bm3 = *(const bf16x8*)(bmp + 24);
    bf16x8 af = *(const bf16x8*)&QS(rqc, h * 32 + g * 8);
    float logit[7][4];
    #pragma unroll
    for (int nt2 = 0; nt2 < 7; nt2++) {
      int rk = nt2 * 16 + li;
      int rkc = rk < 98 ? rk : 97;
      bf16x8 bfr = *(const bf16x8*)&KS(rkc, h * 32 + g * 8);
      f32x4 z = {};
      f32x4 S = mfma16(af, bfr, z);
      #pragma unroll
      for (int vv = 0; vv < 4; vv++) {
        int e = nt2 * 4 + vv;
        float bmv = (e < 8) ? (float)bm0[e] : (e < 16) ? (float)bm1[e - 8]
                  : (e < 24) ? (float)bm2[e - 16] : (float)bm3[e - 24];
        logit[nt2][vv] = S[vv] + bmv;    // Q pre-scaled
      }
    }
    #pragma unroll
    for (int vv = 0; vv < 4; vv++) {
      float mx = logit[0][vv];
      #pragma unroll
      for (int nt2 = 1; nt2 < 7; nt2++) mx = fmaxf(mx, logit[nt2][vv]);
      #pragma unroll
      for (int off = 1; off < 16; off <<= 1) mx = fmaxf(mx, __shfl_xor(mx, off, 64));
      float se = 0.f;
      #pragma unroll
      for (int nt2 = 0; nt2 < 7; nt2++) {
        float p = __expf(logit[nt2][vv] - mx);
        logit[nt2][vv] = p; se += p;
      }
      #pragma unroll
      for (int off = 1; off < 16; off <<= 1) se += __shfl_xor(se, off, 64);
      float inv = 1.0f / se;
      #pragma unroll
      for (int nt2 = 0; nt2 < 7; nt2++) logit[nt2][vv] *= inv;
    }
    // PV chunked through wave-private 16x40 slot (wave-local round trip)
    f32x4 o0 = {}, o1 = {};
    #pragma unroll
    for (int ch = 0; ch < 4; ch++) {
      #pragma unroll
      for (int nl = 0; nl < 2; nl++) {
        int nt2 = ch * 2 + nl;
        #pragma unroll
        for (int vv = 0; vv < 4; vv++) {
          bf16_t pv = (nt2 < 7) ? (bf16_t)logit[nt2][vv] : (bf16_t)0.0f;
          PSc(wid, g * 4 + vv, nl * 16 + li) = pv;
        }
      }
      bf16x8 pf = *(const bf16x8*)&PSc(wid, li, g * 8);
      bf16x8 v0 = *(const bf16x8*)&VT(h * 32 + li, ch * 32 + g * 8);
      bf16x8 v1 = *(const bf16x8*)&VT(h * 32 + 16 + li, ch * 32 + g * 8);
      o0 = mfma16(pf, v0, o0);
      o1 = mfma16(pf, v1, o1);
    }
    // head output overwrites Q's (already-consumed) head-h columns
    #pragma unroll
    for (int vv = 0; vv < 4; vv++) {
      int row = mt * 16 + g * 4 + vv;
      if (row < 98) {
        QS(row, h * 32 + li)      = (bf16_t)o0[vv];
        QS(row, h * 32 + 16 + li) = (bf16_t)o1[vv];
      }
    }
  }
  __syncthreads();                       // BARRIER 3: attn-out complete

  // ---- proj GEMM: C1 = Ao @ wp^T + pb -> Ks overlay ----
  bf16x8 a2[6];
  #pragma unroll
  for (int ks = 0; ks < 6; ks++)
    a2[ks] = *(const bf16x8*)&QS(rqc, ks * 32 + g * 8);
  for (int nt = 0; nt < 3; nt++) {
    const bf16_t* bp0 = wp + ((size_t)nt * 64 + (wn * 2 + 0) * 16 + li) * 192 + g * 8;
    const bf16_t* bp1 = bp0 + 16 * 192;
    f32x4 acc[2] = {};
    #pragma unroll
    for (int ks = 0; ks < 6; ks++) {
      bf16x8 b0 = *(const bf16x8*)(bp0 + ks * 32);
      bf16x8 b1 = *(const bf16x8*)(bp1 + ks * 32);
      acc[0] = mfma16(a2[ks], b0, acc[0]);
      acc[1] = mfma16(a2[ks], b1, acc[1]);
    }
    #pragma unroll
    for (int nl = 0; nl < 2; nl++)
    #pragma unroll
    for (int vv = 0; vv < 4; vv++) {
      int row = wm * 16 + g * 4 + vv;
      if (row < 98) {
        int col = nt * 64 + (wn * 2 + nl) * 16 + li;
        KS(row, col) = (bf16_t)(acc[nl][vv] + pbuf[col]);
      }
    }
  }
  __syncthreads();                       // BARRIER 4: C1 complete

  // ---- fc1 GEMM + GELU + residual ----
  bf16x8 a3[6];
  #pragma unroll
  for (int ks = 0; ks < 6; ks++)
    a3[ks] = *(const bf16x8*)&KS(rqc, ks * 32 + g * 8);
  size_t growv[4];
  #pragma unroll
  for (int vv = 0; vv < 4; vv++) {
    int row = wm * 16 + g * 4 + vv;
    growv[vv] = (row < 98) ? wrow_to_grow(win * 98 + row) : (size_t)0;
  }
  for (int nt = 0; nt < 3; nt++) {
    const bf16_t* bp0 = wf + ((size_t)nt * 64 + (wn * 2 + 0) * 16 + li) * 192 + g * 8;
    const bf16_t* bp1 = bp0 + 16 * 192;
    f32x4 acc[2] = {};
    #pragma unroll
    for (int ks = 0; ks < 6; ks++) {
      bf16x8 b0 = *(const bf16x8*)(bp0 + ks * 32);
      bf16x8 b1 = *(const bf16x8*)(bp1 + ks * 32);
      acc[0] = mfma16(a3[ks], b0, acc[0]);
      acc[1] = mfma16(a3[ks], b1, acc[1]);
    }
    #pragma unroll
    for (int vv = 0; vv < 4; vv++) {
      int row = wm * 16 + g * 4 + vv;
      if (row < 98) {
        const float* xrr = x + growv[vv] * 192;
        float* op = out + growv[vv] * 192;
        #pragma unroll
        for (int nl = 0; nl < 2; nl++) {
          int col = nt * 64 + (wn * 2 + nl) * 16 + li;
          float val = acc[nl][vv] + fbuf[col];
          float ge = 0.5f * val * (1.0f + erff(val * 0.70710678118654752f));
          op[col] = xrr[col] + ge;
        }
      }
    }
  }
  #undef PSc
  #undef QS
  #undef KS
  #undef VT
}

// ---------------- launch ----------------
extern "C" void kernel_launch(void* const* d_in, const int* in_sizes, int n_in,
                              void* d_out, int out_size, void* d_ws, size_t ws_size,
                              hipStream_t stream) {
  (void)in_sizes; (void)n_in; (void)out_size; (void)ws_size;
  const float* x         = (const float*)d_in[0];
  const float* attn_mask = (const float*)d_in[1];
  const float* n1g       = (const float*)d_in[2];
  const float* n1b       = (const float*)d_in[3];
  const float* qkv_w     = (const float*)d_in[4];
  const float* qkv_b     = (const float*)d_in[5];
  const float* rel_bias  = (const float*)d_in[6];
  const float* proj_w    = (const float*)d_in[7];
  const float* proj_b    = (const float*)d_in[8];
  const float* fc1_w     = (const float*)d_in[9];
  const float* fc1_b     = (const float*)d_in[10];
  float* out = (float*)d_out;

  char* ws = (char*)d_ws;
  size_t off = 0;
  auto alloc = [&](size_t bytes) -> char* {
    char* p = ws + off;
    off += (bytes + 255) & ~(size_t)255;
    return p;
  };
  bf16_t* wq  = (bf16_t*)alloc(110592 * 2);
  bf16_t* wp  = (bf16_t*)alloc(36864 * 2);
  bf16_t* wf  = (bf16_t*)alloc(36864 * 2);
  bf16_t* bmr = (bf16_t*)alloc((size_t)688128 * 2);

  prep_all_kernel<<<3408, 256, 0, stream>>>(qkv_w, proj_w, fc1_w, rel_bias,
                                            attn_mask, wq, wp, wf, bmr);
  fused_kernel<<<1024, 896, 0, stream>>>(x, n1g, n1b, wq, qkv_b, wp, proj_b,
                                         wf, fc1_b, bmr, out);
}

// Round 6
// 382.354 us; speedup vs baseline: 1.3432x; 1.3432x over previous
//
#include <hip/hip_runtime.h>
#include <cstdint>
#include <cstddef>

typedef __bf16 bf16_t;
typedef __bf16 bf16x8 __attribute__((ext_vector_type(8)));
typedef float  f32x4  __attribute__((ext_vector_type(4)));

#define DHW   25088
#define SCALE 0.17677669529663687f  /* 32^-0.5 */

__device__ inline f32x4 mfma16(bf16x8 a, bf16x8 b, f32x4 c) {
  return __builtin_amdgcn_mfma_f32_16x16x32_bf16(a, b, c, 0, 0, 0);
}

// window-order row -> global (rolled) token row
__device__ inline size_t wrow_to_grow(int orow) {
  int win = orow / 98, tok = orow % 98;
  int b = win >> 8, wr = win & 255;
  int bd = wr >> 6, bh = (wr >> 3) & 7, bwi = wr & 7;
  int md = tok / 49, mh = (tok / 7) % 7, mw = tok % 7;
  int d = (bd * 2 + md + 1) & 7;
  int h = bh * 7 + mh + 3; if (h >= 56) h -= 56;
  int w = bwi * 7 + mw + 3; if (w >= 56) w -= 56;
  return (size_t)b * DHW + (size_t)((d * 56 + h) * 56 + w);
}

// ---------------- K0: weight cast + bias/mask table (merged) ----------
__global__ __launch_bounds__(256) void prep_all_kernel(
    const float* __restrict__ qkv_w, const float* __restrict__ proj_w,
    const float* __restrict__ fc1_w, const float* __restrict__ rel_bias,
    const float* __restrict__ mask,
    bf16_t* __restrict__ wq, bf16_t* __restrict__ wp, bf16_t* __restrict__ wf,
    bf16_t* __restrict__ bmr)
{
  int idx = blockIdx.x * 256 + threadIdx.x;
  if (idx < 110592) { wq[idx] = (bf16_t)qkv_w[idx]; return; }
  idx -= 110592;
  if (idx < 36864) { wp[idx] = (bf16_t)proj_w[idx]; return; }
  idx -= 36864;
  if (idx < 36864) { wf[idx] = (bf16_t)fc1_w[idx]; return; }
  idx -= 36864;
  if (idx >= 688128) return;
  int e    = idx & 31;
  int lane = (idx >> 5) & 63;
  int t2   = idx >> 11;
  int mt   = t2 % 7;
  int wh   = t2 / 7;
  int type = wh / 6, h = wh - type * 6;
  int winb = ((type & 4) ? 3 : 0) * 64 + ((type & 2) ? 7 : 0) * 8 + ((type & 1) ? 7 : 0);
  int g = lane >> 4, li = lane & 15;
  int nt2 = e >> 2, v = e & 3;
  int row = mt * 16 + g * 4 + v;
  int col = nt2 * 16 + li;
  float val = -1e30f;
  if (row < 98 && col < 98 && nt2 < 7) {
    int di = row / 49 - col / 49 + 1;
    int hi = (row / 7) % 7 - (col / 7) % 7 + 6;
    int wi = row % 7 - col % 7 + 6;
    int rid = di * 169 + hi * 13 + wi;
    val = mask[winb * 9604 + row * 98 + col] + rel_bias[rid * 6 + h];
  }
  bmr[idx] = (bf16_t)val;
}

// ---------------- K1: fused per-window block, 14 waves, ~23 barriers --
// wave = (wm, wn); heads for wave = {wn, 2+wn, 4+wn} so Q stays wave-local
// (reg-held, transposed via wave-private PSc slot). 128-col staging phases.
// LDS: staging(128x200) | Ks(K->C1) | Vt(->AoS frag exchange) | biases.
__global__ __launch_bounds__(896) void fused_kernel(
    const float* __restrict__ x, const float* __restrict__ gw,
    const float* __restrict__ bw_, const bf16_t* __restrict__ wq,
    const float* __restrict__ qkv_b, const bf16_t* __restrict__ wp,
    const float* __restrict__ proj_b, const bf16_t* __restrict__ wf,
    const float* __restrict__ fc1_b, const bf16_t* __restrict__ bmr,
    float* __restrict__ out)
{
  __shared__ __align__(16) char smem[146464];
  bf16_t* U   = (bf16_t*)smem;                 // 51200: Bs[128][200] | PSc | gwb
  bf16_t* Ks  = (bf16_t*)(smem + 51200);       // 39200: K -> C1 (proj out)
  bf16_t* Vt  = (bf16_t*)(smem + 90400);       // 52224: V^T [d][tok] -> AoS
  bf16_t* AoS = (bf16_t*)(smem + 90400);       // overlay: 42 frag slots x 1KB
  float*  qb  = (float*)(smem + 142624);       // 576 f32 qkv bias
  float*  pbuf= (float*)(smem + 144928);       // 192 f32 proj bias
  float*  fbuf= (float*)(smem + 145696);       // 192 f32 fc1 bias
  float*  gwb = (float*)smem;                  // 384 f32 LN gamma/beta (on U)

  #define BS(r, c)     U[(r) * 200 + (c)]
  #define PSc(w, r, c) U[(w) * 640 + (r) * 40 + (c)]
  #define KS(r, c)     Ks[(r) * 200 + (c)]
  #define C1M(r, c)    Ks[(r) * 200 + (c)]
  #define VT(d, t)     Vt[(d) * 136 + (t)]

  int win  = blockIdx.x;
  int winb = win & 255;
  int type = (((winb >> 6) == 3) ? 4 : 0) | ((((winb >> 3) & 7) == 7) ? 2 : 0)
           | (((winb & 7) == 7) ? 1 : 0);
  int tid  = threadIdx.x;
  int wid  = tid >> 6, lane = tid & 63;
  int wn = wid & 1, wm = wid >> 1;             // wm 0..6, wn 0..1
  int g = lane >> 4, li = lane & 15;

  // small tables + V token-pad zero (cols 96..127; 96,97 overwritten by real V)
  if (tid < 192) { gwb[tid] = gw[tid]; gwb[192 + tid] = bw_[tid]; }
  if (tid < 576) qb[tid] = qkv_b[tid];
  if (tid >= 576 && tid < 768) pbuf[tid - 576] = proj_b[tid - 576];
  if (tid >= 768) fbuf[tid - 768] = fc1_b[tid - 768];
  if (tid < 64) fbuf[128 + tid] = fc1_b[128 + tid];
  if (tid < 768) {
    uint4 z = {0u, 0u, 0u, 0u};
    int d = tid >> 2, part = tid & 3;
    *(uint4*)&VT(d, 96 + part * 8) = z;
  }

  // ---- LN -> A fragments in registers (duplicated per wn) ----
  int r = wm * 16 + li;
  float v[48];
  if (r < 98) {
    size_t growr = wrow_to_grow(win * 98 + r);
    const float* xr = x + growr * 192 + g * 8;
    #pragma unroll
    for (int ks = 0; ks < 6; ks++) {
      *(float4*)&v[ks * 8]     = *(const float4*)(xr + ks * 32);
      *(float4*)&v[ks * 8 + 4] = *(const float4*)(xr + ks * 32 + 4);
    }
  } else {
    #pragma unroll
    for (int i = 0; i < 48; i++) v[i] = 0.f;
  }
  float s = 0.f, sq = 0.f;
  #pragma unroll
  for (int i = 0; i < 48; i++) { s += v[i]; sq += v[i] * v[i]; }
  s += __shfl_xor(s, 16, 64); sq += __shfl_xor(sq, 16, 64);
  s += __shfl_xor(s, 32, 64); sq += __shfl_xor(sq, 32, 64);
  float mu   = s * (1.0f / 192.0f);
  float var  = sq * (1.0f / 192.0f) - mu * mu;
  float rstd = rsqrtf(var + 1e-5f);
  __syncthreads();                       // B1: tables staged
  bf16x8 afr[6];
  #pragma unroll
  for (int ks = 0; ks < 6; ks++) {
    bf16x8 t;
    #pragma unroll
    for (int j = 0; j < 8; j++) {
      int c = ks * 32 + g * 8 + j;
      t[j] = (r < 98) ? (bf16_t)((v[ks * 8 + j] - mu) * rstd * gwb[c] + gwb[192 + c])
                      : (bf16_t)0.0f;
    }
    afr[ks] = t;
  }

  uint4 st[4];
  auto loadw = [&](const bf16_t* w, int row0, int nrows) {
    int tot = nrows * 24;
    #pragma unroll
    for (int i = 0; i < 4; i++) {
      int c = tid + 896 * i;
      if (c < tot) {
        int rr = c / 24, ck = c % 24;
        st[i] = *(const uint4*)(w + (size_t)(row0 + rr) * 192 + ck * 8);
      }
    }
  };
  auto storebs = [&](int nrows) {
    int tot = nrows * 24;
    #pragma unroll
    for (int i = 0; i < 4; i++) {
      int c = tid + 896 * i;
      if (c < tot) {
        int rr = c / 24, ck = c % 24;
        *(uint4*)&BS(rr, ck * 8) = st[i];
      }
    }
  };

  // ---- QKV GEMM: 5 phases of 128 (last 64) cols -> qh regs / Ks / Vt ----
  bf16x8 qh[3];
  loadw(wq, 0, 128);
  #pragma unroll
  for (int p = 0; p < 5; p++) {
    const int cnt = (p < 4) ? 2 : 1;
    __syncthreads();                     // prev Bs readers done (p=0: gwb dead)
    storebs(cnt * 64);
    __syncthreads();
    if (p < 4) loadw(wq, (p + 1) * 128, (p < 3) ? 128 : 64);
    #pragma unroll
    for (int tt = 0; tt < cnt; tt++) {
      const int nt = 2 * p + tt;
      f32x4 acc[2] = {};
      #pragma unroll
      for (int ks = 0; ks < 6; ks++) {
        bf16x8 a = afr[ks];
        bf16x8 b0 = *(const bf16x8*)&BS(tt * 64 + wn * 32 + li, ks * 32 + g * 8);
        bf16x8 b1 = *(const bf16x8*)&BS(tt * 64 + wn * 32 + 16 + li, ks * 32 + g * 8);
        acc[0] = mfma16(a, b0, acc[0]);
        acc[1] = mfma16(a, b1, acc[1]);
      }
      if (nt < 3) {                      // Q tile: head 2nt+wn, keep in regs
        bf16x8 t;
        #pragma unroll
        for (int nl = 0; nl < 2; nl++)
        #pragma unroll
        for (int vv = 0; vv < 4; vv++)
          t[nl * 4 + vv] = (bf16_t)((acc[nl][vv]
                             + qb[nt * 64 + wn * 32 + nl * 16 + li]) * SCALE);
        qh[nt] = t;
      } else {
        #pragma unroll
        for (int nl = 0; nl < 2; nl++)
        #pragma unroll
        for (int vv = 0; vv < 4; vv++) {
          int row = wm * 16 + g * 4 + vv;
          if (row < 98) {
            int col = nt * 64 + wn * 32 + nl * 16 + li;
            float val = acc[nl][vv] + qb[col];
            if (nt < 6) KS(row, col - 192) = (bf16_t)val;
            else        VT(col - 384, row) = (bf16_t)val;
          }
        }
      }
    }
  }
  __syncthreads();                       // B12: K/V staged; U free for PSc
  loadw(wp, 0, 128);                     // proj weights in flight over attention

  // ---- attention: wave (wm, wn) -> heads {wn, 2+wn, 4+wn} ----
  int rq  = wm * 16 + li;
  int rqc = rq < 98 ? rq : 97;
  bf16x8 of[3];
  #pragma unroll
  for (int hp = 0; hp < 3; hp++) {
    const int h = 2 * hp + wn;
    const bf16_t* bmp = bmr + ((((size_t)(type * 6 + h)) * 7 + wm) * 64 + lane) * 32;
    bf16x8 bm0 = *(const bf16x8*)(bmp);
    bf16x8 bm1 = *(const bf16x8*)(bmp + 8);
    bf16x8 bm2 = *(const bf16x8*)(bmp + 16);
    bf16x8 bm3 = *(const bf16x8*)(bmp + 24);
    // Q reg -> A-frag via wave-private PSc transpose (in-order DS)
    #pragma unroll
    for (int j = 0; j < 8; j++)
      PSc(wid, g * 4 + (j & 3), (j >> 2) * 16 + li) = qh[hp][j];
    bf16x8 af = *(const bf16x8*)&PSc(wid, li, g * 8);
    float logit[7][4];
    #pragma unroll
    for (int nt2 = 0; nt2 < 7; nt2++) {
      int rk = nt2 * 16 + li;
      int rkc = rk < 98 ? rk : 97;
      bf16x8 bfr = *(const bf16x8*)&KS(rkc, h * 32 + g * 8);
      f32x4 z = {};
      f32x4 S = mfma16(af, bfr, z);
      #pragma unroll
      for (int vv = 0; vv < 4; vv++) {
        int e = nt2 * 4 + vv;
        float bmv = (e < 8) ? (float)bm0[e] : (e < 16) ? (float)bm1[e - 8]
                  : (e < 24) ? (float)bm2[e - 16] : (float)bm3[e - 24];
        logit[nt2][vv] = S[vv] + bmv;    // Q pre-scaled
      }
    }
    #pragma unroll
    for (int vv = 0; vv < 4; vv++) {
      float mx = logit[0][vv];
      #pragma unroll
      for (int nt2 = 1; nt2 < 7; nt2++) mx = fmaxf(mx, logit[nt2][vv]);
      #pragma unroll
      for (int off = 1; off < 16; off <<= 1) mx = fmaxf(mx, __shfl_xor(mx, off, 64));
      float se = 0.f;
      #pragma unroll
      for (int nt2 = 0; nt2 < 7; nt2++) {
        float p = __expf(logit[nt2][vv] - mx);
        logit[nt2][vv] = p; se += p;
      }
      #pragma unroll
      for (int off = 1; off < 16; off <<= 1) se += __shfl_xor(se, off, 64);
      float inv = 1.0f / se;
      #pragma unroll
      for (int nt2 = 0; nt2 < 7; nt2++) logit[nt2][vv] *= inv;
    }
    // PV chunked through wave-private PSc slot (wave-local round trip)
    f32x4 o0 = {}, o1 = {};
    #pragma unroll
    for (int ch = 0; ch < 4; ch++) {
      #pragma unroll
      for (int nl = 0; nl < 2; nl++) {
        int nt2 = ch * 2 + nl;
        #pragma unroll
        for (int vv = 0; vv < 4; vv++) {
          bf16_t pv = (nt2 < 7) ? (bf16_t)logit[nt2][vv] : (bf16_t)0.0f;
          PSc(wid, g * 4 + vv, nl * 16 + li) = pv;
        }
      }
      bf16x8 pf = *(const bf16x8*)&PSc(wid, li, g * 8);
      bf16x8 v0 = *(const bf16x8*)&VT(h * 32 + li, ch * 32 + g * 8);
      bf16x8 v1 = *(const bf16x8*)&VT(h * 32 + 16 + li, ch * 32 + g * 8);
      o0 = mfma16(pf, v0, o0);
      o1 = mfma16(pf, v1, o1);
    }
    bf16x8 t;
    #pragma unroll
    for (int vv = 0; vv < 4; vv++) {
      t[vv]     = (bf16_t)o0[vv];
      t[4 + vv] = (bf16_t)o1[vv];
    }
    of[hp] = t;
  }
  __syncthreads();                       // B13: all Ks/Vt/PSc reads done

  // frag exchange: attn-out -> AoS (on dead Vt) -> proj A-frags
  #pragma unroll
  for (int hp = 0; hp < 3; hp++) {
    const int h = 2 * hp + wn;
    bf16_t* slot = AoS + (size_t)(wm * 6 + h) * 512;
    #pragma unroll
    for (int j = 0; j < 8; j++)
      slot[(g * 4 + (j & 3)) * 32 + (j >> 2) * 16 + li] = of[hp][j];
  }
  __syncthreads();                       // B14: AoS visible
  bf16x8 a2[6];
  #pragma unroll
  for (int ks = 0; ks < 6; ks++)
    a2[ks] = *(const bf16x8*)(AoS + (size_t)(wm * 6 + ks) * 512 + li * 32 + g * 8);

  // ---- proj GEMM: C1 = Ao @ wp^T + pb -> Ks overlay ----
  #pragma unroll
  for (int p = 0; p < 2; p++) {
    const int cnt = (p == 0) ? 2 : 1;
    __syncthreads();
    storebs(cnt * 64);
    __syncthreads();
    if (p == 0) loadw(wp, 128, 64);
    else        loadw(wf, 0, 128);       // fc1 weights in flight
    #pragma unroll
    for (int tt = 0; tt < cnt; tt++) {
      const int nt = 2 * p + tt;
      f32x4 acc[2] = {};
      #pragma unroll
      for (int ks = 0; ks < 6; ks++) {
        bf16x8 b0 = *(const bf16x8*)&BS(tt * 64 + wn * 32 + li, ks * 32 + g * 8);
        bf16x8 b1 = *(const bf16x8*)&BS(tt * 64 + wn * 32 + 16 + li, ks * 32 + g * 8);
        acc[0] = mfma16(a2[ks], b0, acc[0]);
        acc[1] = mfma16(a2[ks], b1, acc[1]);
      }
      #pragma unroll
      for (int nl = 0; nl < 2; nl++)
      #pragma unroll
      for (int vv = 0; vv < 4; vv++) {
        int row = wm * 16 + g * 4 + vv;
        if (row < 98) {
          int col = nt * 64 + wn * 32 + nl * 16 + li;
          C1M(row, col) = (bf16_t)(acc[nl][vv] + pbuf[col]);
        }
      }
    }
  }
  __syncthreads();                       // B19: C1 complete

  // ---- fc1 GEMM + GELU + residual ----
  bf16x8 a3[6];
  #pragma unroll
  for (int ks = 0; ks < 6; ks++)
    a3[ks] = *(const bf16x8*)&C1M(rqc, ks * 32 + g * 8);
  size_t growv[4];
  #pragma unroll
  for (int vv = 0; vv < 4; vv++) {
    int row = wm * 16 + g * 4 + vv;
    growv[vv] = (row < 98) ? wrow_to_grow(win * 98 + row) : (size_t)0;
  }
  #pragma unroll
  for (int p = 0; p < 2; p++) {
    const int cnt = (p == 0) ? 2 : 1;
    __syncthreads();
    storebs(cnt * 64);
    __syncthreads();
    if (p == 0) loadw(wf, 128, 64);
    #pragma unroll
    for (int tt = 0; tt < cnt; tt++) {
      const int nt = 2 * p + tt;
      f32x4 acc[2] = {};
      #pragma unroll
      for (int ks = 0; ks < 6; ks++) {
        bf16x8 b0 = *(const bf16x8*)&BS(tt * 64 + wn * 32 + li, ks * 32 + g * 8);
        bf16x8 b1 = *(const bf16x8*)&BS(tt * 64 + wn * 32 + 16 + li, ks * 32 + g * 8);
        acc[0] = mfma16(a3[ks], b0, acc[0]);
        acc[1] = mfma16(a3[ks], b1, acc[1]);
      }
      #pragma unroll
      for (int vv = 0; vv < 4; vv++) {
        int row = wm * 16 + g * 4 + vv;
        if (row < 98) {
          const float* xrr = x + growv[vv] * 192;
          float* op = out + growv[vv] * 192;
          #pragma unroll
          for (int nl = 0; nl < 2; nl++) {
            int col = nt * 64 + wn * 32 + nl * 16 + li;
            float val = acc[nl][vv] + fbuf[col];
            float ge = 0.5f * val * (1.0f + erff(val * 0.70710678118654752f));
            op[col] = xrr[col] + ge;
          }
        }
      }
    }
  }
  #undef BS
  #undef PSc
  #undef KS
  #undef C1M
  #undef VT
}

// ---------------- launch ----------------
extern "C" void kernel_launch(void* const* d_in, const int* in_sizes, int n_in,
                              void* d_out, int out_size, void* d_ws, size_t ws_size,
                              hipStream_t stream) {
  (void)in_sizes; (void)n_in; (void)out_size; (void)ws_size;
  const float* x         = (const float*)d_in[0];
  const float* attn_mask = (const float*)d_in[1];
  const float* n1g       = (const float*)d_in[2];
  const float* n1b       = (const float*)d_in[3];
  const float* qkv_w     = (const float*)d_in[4];
  const float* qkv_b     = (const float*)d_in[5];
  const float* rel_bias  = (const float*)d_in[6];
  const float* proj_w    = (const float*)d_in[7];
  const float* proj_b    = (const float*)d_in[8];
  const float* fc1_w     = (const float*)d_in[9];
  const float* fc1_b     = (const float*)d_in[10];
  float* out = (float*)d_out;

  char* ws = (char*)d_ws;
  size_t off = 0;
  auto alloc = [&](size_t bytes) -> char* {
    char* p = ws + off;
    off += (bytes + 255) & ~(size_t)255;
    return p;
  };
  bf16_t* wq  = (bf16_t*)alloc(110592 * 2);
  bf16_t* wp  = (bf16_t*)alloc(36864 * 2);
  bf16_t* wf  = (bf16_t*)alloc(36864 * 2);
  bf16_t* bmr = (bf16_t*)alloc((size_t)688128 * 2);

  prep_all_kernel<<<3408, 256, 0, stream>>>(qkv_w, proj_w, fc1_w, rel_bias,
                                            attn_mask, wq, wp, wf, bmr);
  fused_kernel<<<1024, 896, 0, stream>>>(x, n1g, n1b, wq, qkv_b, wp, proj_b,
                                         wf, fc1_b, bmr, out);
}